// Round 3
// baseline (2496.963 us; speedup 1.0000x reference)
//
#include <hip/hip_runtime.h>

// AdaptiveGraphConvolution on MI355X (gfx950)
// out = sum_l m_l * (A_l @ x) @ W_l + bias
//
// R3: zero global atomics. 16-row bucket sort built with LDS histograms
// (hist was 131us / 99.6MB atomic write-through; fills were 4x800K atomics),
// then ONE fused kernel: per-bucket LDS SpMM accumulate (ds_add_f32) +
// W-projection + graph mix + bias, out written exactly once.
// 4 launches total, ~30.7 MB workspace.

constexpr int N = 50000;
constexpr int E = 800000;
constexpr int D = 128;
constexpr int L = 4;
constexpr int BSH = 4;             // 16 rows per bucket
constexpr int NB = N >> BSH;       // 3125 buckets (exact: 3125*16 = 50000)
constexpr int NCHK = 100;          // edge chunks per graph
constexpr int CHUNK = E / NCHK;    // 8000 edges per chunk (exact)

// ---------------------------------------------------------------------------
// A) Per-chunk bucket histogram (LDS only). pcnt[g][blk][b], coalesced write.
// ---------------------------------------------------------------------------
__global__ __launch_bounds__(256) void bucket_hist_kernel(
    const int* __restrict__ edge_rows,   // [L][E]
    int* __restrict__ pcnt)              // [L][NCHK][NB]
{
    __shared__ int cnt[NB];
    const int blk = blockIdx.x, g = blockIdx.y, tid = threadIdx.x;
    for (int i = tid; i < NB; i += 256) cnt[i] = 0;
    __syncthreads();
    const int* rows = edge_rows + (size_t)g * E + (size_t)blk * CHUNK;
    for (int i = tid; i < CHUNK; i += 256)
        atomicAdd(&cnt[rows[i] >> BSH], 1);
    __syncthreads();
    int* outp = pcnt + ((size_t)g * NCHK + blk) * NB;
    for (int i = tid; i < NB; i += 256) outp[i] = cnt[i];
}

// ---------------------------------------------------------------------------
// B) Per-graph: pcnt -> per-block exclusive prefix (in place, per bucket
//    column) and bucket starts bstart[g][NB+1]. One 1024-thread block/graph.
// ---------------------------------------------------------------------------
__global__ __launch_bounds__(1024) void scan_kernel(
    int* __restrict__ pcnt,      // [L][NCHK][NB]
    int* __restrict__ bstart)    // [L][NB+1]
{
    __shared__ int sums[1024];
    const int g = blockIdx.x, t = threadIdx.x;
    int tot[4];
    int s = 0;
#pragma unroll
    for (int bb = 0; bb < 4; ++bb) {
        int b = t * 4 + bb;
        int run = 0;
        if (b < NB) {
            int* p = pcnt + (size_t)g * NCHK * NB + b;
            for (int blk = 0; blk < NCHK; ++blk) {
                int v = p[(size_t)blk * NB];
                p[(size_t)blk * NB] = run;   // per-block offset within bucket
                run += v;
            }
        }
        tot[bb] = run;
        s += run;
    }
    sums[t] = s;
    __syncthreads();
    for (int off = 1; off < 1024; off <<= 1) {
        int v = (t >= off) ? sums[t - off] : 0;
        __syncthreads();
        sums[t] += v;
        __syncthreads();
    }
    int ex = (t == 0) ? 0 : sums[t - 1];
    int* bs = bstart + (size_t)g * (NB + 1);
#pragma unroll
    for (int bb = 0; bb < 4; ++bb) {
        int b = t * 4 + bb;
        if (b < NB) { bs[b] = ex; ex += tot[bb]; }
    }
    if (t == 0) bs[NB] = E;
}

// ---------------------------------------------------------------------------
// C) Bucket-sorted fill: pairs[g][pos] = {col | rowloc<<16, val_bits}.
//    Position = bstart + per-block prefix + LDS rank. No global atomics.
// ---------------------------------------------------------------------------
__global__ __launch_bounds__(256) void fill_kernel(
    const int* __restrict__ edge_rows,
    const int* __restrict__ edge_cols,
    const float* __restrict__ edge_vals,
    const int* __restrict__ pcnt,
    const int* __restrict__ bstart,
    int2* __restrict__ pairs)            // [L][E]
{
    __shared__ int base[NB];
    __shared__ int cur[NB];
    const int blk = blockIdx.x, g = blockIdx.y, tid = threadIdx.x;
    const int* pc = pcnt + ((size_t)g * NCHK + blk) * NB;
    const int* bs = bstart + (size_t)g * (NB + 1);
    for (int i = tid; i < NB; i += 256) {
        base[i] = bs[i] + pc[i];
        cur[i] = 0;
    }
    __syncthreads();
    const size_t eoff = (size_t)g * E + (size_t)blk * CHUNK;
    const int* rows = edge_rows + eoff;
    const int* cols = edge_cols + eoff;
    const float* vals = edge_vals + eoff;
    int2* pg = pairs + (size_t)g * E;
    for (int i = tid; i < CHUNK; i += 256) {
        int r = rows[i];
        int b = r >> BSH;
        int rank = atomicAdd(&cur[b], 1);
        pg[base[b] + rank] = make_int2(cols[i] | ((r & 15) << 16),
                                       __float_as_int(vals[i]));
    }
}

// ---------------------------------------------------------------------------
// D) Fused SpMM + projection. One block per bucket (16 output rows).
//    Per graph: LDS acc[16][128] via ds_add_f32 (lane covers f=lane,lane+64:
//    2-way bank alias = free), then out-acc (registers, bias-initialized)
//    += acc @ (m_l * W_l) via 16KB LDS W chunks. Single out write.
// ---------------------------------------------------------------------------
__global__ __launch_bounds__(256) void spmm_proj_kernel(
    const float* __restrict__ x,
    const int2* __restrict__ pairs,     // [L][E]
    const int* __restrict__ bstart,     // [L][NB+1]
    const float* __restrict__ W,        // [L][D][D]
    const float* __restrict__ mix,      // [L]
    const float* __restrict__ bias,     // [D]
    float* __restrict__ out)            // [N][D]
{
    __shared__ float acc[16][D];   //  8 KB
    __shared__ float wc[32][D];    // 16 KB
    const int b = blockIdx.x, tid = threadIdx.x;
    const int lane = tid & 63, wave = tid >> 6;
    const int r0 = wave * 4;

    float a0[4], a1[4];
    {
        float bl = bias[lane], bh = bias[lane + 64];
#pragma unroll
        for (int r = 0; r < 4; ++r) { a0[r] = bl; a1[r] = bh; }
    }

    for (int l = 0; l < L; ++l) {
        for (int i = tid; i < 16 * D; i += 256) ((float*)acc)[i] = 0.f;
        __syncthreads();

        const int beg = bstart[l * (NB + 1) + b];
        const int end = bstart[l * (NB + 1) + b + 1];
        const int2* pg = pairs + (size_t)l * E;
        for (int j = beg + wave; j < end; j += 4) {
            int2 p = pg[j];
            int col = p.x & 0xFFFF;
            int rl  = p.x >> 16;
            float v = __int_as_float(p.y);
            float x0 = x[col * D + lane];
            float x1 = x[col * D + 64 + lane];
            atomicAdd(&acc[rl][lane],      v * x0);
            atomicAdd(&acc[rl][64 + lane], v * x1);
        }
        __syncthreads();

        const float m = mix[l];
        const float4* wsrc = reinterpret_cast<const float4*>(W + (size_t)l * D * D);
        for (int kc = 0; kc < 4; ++kc) {
            for (int i = tid; i < 1024; i += 256) {
                float4 t = wsrc[kc * 1024 + i];
                ((float4*)wc)[i] = make_float4(m * t.x, m * t.y, m * t.z, m * t.w);
            }
            __syncthreads();
#pragma unroll
            for (int d4 = 0; d4 < 8; ++d4) {
                float4 av[4];
#pragma unroll
                for (int r = 0; r < 4; ++r)
                    av[r] = *reinterpret_cast<const float4*>(&acc[r0 + r][kc * 32 + d4 * 4]);
#pragma unroll
                for (int jj = 0; jj < 4; ++jj) {
                    float w0 = wc[d4 * 4 + jj][lane];
                    float w1 = wc[d4 * 4 + jj][64 + lane];
#pragma unroll
                    for (int r = 0; r < 4; ++r) {
                        float s = (jj == 0) ? av[r].x
                                : (jj == 1) ? av[r].y
                                : (jj == 2) ? av[r].z
                                            : av[r].w;
                        a0[r] = fmaf(s, w0, a0[r]);
                        a1[r] = fmaf(s, w1, a1[r]);
                    }
                }
            }
            __syncthreads();
        }
    }

    const int row0 = b * 16 + r0;
#pragma unroll
    for (int r = 0; r < 4; ++r) {
        out[(size_t)(row0 + r) * D + lane]      = a0[r];
        out[(size_t)(row0 + r) * D + 64 + lane] = a1[r];
    }
}

extern "C" void kernel_launch(void* const* d_in, const int* in_sizes, int n_in,
                              void* d_out, int out_size, void* d_ws, size_t ws_size,
                              hipStream_t stream)
{
    const float* x         = (const float*)d_in[0];
    const int*   edge_rows = (const int*)d_in[1];
    const int*   edge_cols = (const int*)d_in[2];
    const float* edge_vals = (const float*)d_in[3];
    const float* W         = (const float*)d_in[4];
    const float* mix       = (const float*)d_in[5];
    const float* bias      = (const float*)d_in[6];
    float* out = (float*)d_out;

    // Workspace (~30.7 MB): pairs [L][E] int2 (25.6 MB) | pcnt [L][NCHK][NB]
    // (5.0 MB) | bstart [L][NB+1] (50 KB). All fully rewritten every call.
    int2* pairs = (int2*)d_ws;
    int*  pcnt  = (int*)(pairs + (size_t)L * E);
    int*  bstart = pcnt + (size_t)L * NCHK * NB;

    bucket_hist_kernel<<<dim3(NCHK, L), 256, 0, stream>>>(edge_rows, pcnt);
    scan_kernel<<<L, 1024, 0, stream>>>(pcnt, bstart);
    fill_kernel<<<dim3(NCHK, L), 256, 0, stream>>>(edge_rows, edge_cols,
                                                   edge_vals, pcnt, bstart, pairs);
    spmm_proj_kernel<<<NB, 256, 0, stream>>>(x, pairs, bstart, W, mix, bias, out);
}

// Round 4
// 721.096 us; speedup vs baseline: 3.4627x; 3.4627x over previous
//
#include <hip/hip_runtime.h>

// AdaptiveGraphConvolution on MI355X (gfx950)
// out = sum_l m_l * (A_l @ x) @ W_l + bias
//
// R4: atomic-free bucket build (R3) + per-row register gather (R2) + fused
// projection. Edges bucket-sorted (16 rows/bucket) as packed 4B indices;
// fused kernel counting-sorts each bucket by row in LDS, gathers bf16 x
// rows into registers (one wave = 4 rows), then GEMM-accumulates through
// LDS-staged W with bias folded in. Zero global atomics, zero LDS-atomic
// accumulation, out written exactly once. 6 launches, ~30.7 MB workspace.

constexpr int N = 50000;
constexpr int E = 800000;
constexpr int D = 128;
constexpr int L = 4;
constexpr int BSH = 4;            // 16 rows per bucket
constexpr int NB = N >> BSH;      // 3125 buckets (exact)
constexpr int NCHK = 100;         // chunks per graph
constexpr int CHUNK = E / NCHK;   // 8000 edges per chunk (exact)
constexpr int CAP = 1024;         // staged edges per bucket (avg 256; P(>1024)~0)

// ---------------------------------------------------------------------------
// 0) x f32 -> bf16 (RNE), packed 2/uint. grid = N*D/2/256.
// ---------------------------------------------------------------------------
__device__ inline unsigned bf16rne(unsigned u) {
    return (u + 0x7FFFu + ((u >> 16) & 1u)) >> 16;
}
__global__ __launch_bounds__(256) void cvt_x_kernel(
    const float* __restrict__ x, unsigned* __restrict__ xb)
{
    int i = blockIdx.x * 256 + threadIdx.x;   // uint index, 2 floats each
    float2 v = reinterpret_cast<const float2*>(x)[i];
    unsigned lo = bf16rne(__float_as_uint(v.x));
    unsigned hi = bf16rne(__float_as_uint(v.y));
    xb[i] = lo | (hi << 16);
}

// ---------------------------------------------------------------------------
// 1) Per-chunk bucket histogram (LDS only). pcnt[g][chk][b].
// ---------------------------------------------------------------------------
__global__ __launch_bounds__(256) void bucket_hist_kernel(
    const int* __restrict__ edge_rows, unsigned* __restrict__ pcnt)
{
    __shared__ int cnt[NB];
    const int blk = blockIdx.x, g = blockIdx.y, tid = threadIdx.x;
    for (int i = tid; i < NB; i += 256) cnt[i] = 0;
    __syncthreads();
    const int* rows = edge_rows + (size_t)g * E + (size_t)blk * CHUNK;
    for (int i = tid; i < CHUNK; i += 256)
        atomicAdd(&cnt[rows[i] >> BSH], 1);
    __syncthreads();
    unsigned* outp = pcnt + ((size_t)g * NCHK + blk) * NB;
    for (int i = tid; i < NB; i += 256) outp[i] = cnt[i];
}

// ---------------------------------------------------------------------------
// 2a) Column pass: pcnt -> per-chunk offsets (in place); bucket totals ->
//     bstart[g][b] (temp). One thread per (g,b); coalesced over b.
// ---------------------------------------------------------------------------
__global__ __launch_bounds__(256) void scan1_kernel(
    unsigned* __restrict__ pcnt, int* __restrict__ bstart)
{
    const int b = blockIdx.x * 256 + threadIdx.x;
    const int g = blockIdx.y;
    if (b >= NB) return;
    unsigned run = 0;
    unsigned* p = pcnt + (size_t)g * NCHK * NB + b;
    for (int blk = 0; blk < NCHK; ++blk) {
        unsigned v = p[(size_t)blk * NB];
        p[(size_t)blk * NB] = run;
        run += v;
    }
    bstart[(size_t)g * (NB + 1) + b] = (int)run;
}

// ---------------------------------------------------------------------------
// 2b) Per-graph exclusive scan of bucket totals (in place). grid = L.
// ---------------------------------------------------------------------------
__global__ __launch_bounds__(1024) void scan2_kernel(int* __restrict__ bstart)
{
    __shared__ int sums[1024];
    int* bs = bstart + (size_t)blockIdx.x * (NB + 1);
    const int t = threadIdx.x;
    int tv[4];
    int s = 0;
#pragma unroll
    for (int i = 0; i < 4; ++i) {
        int idx = t * 4 + i;
        tv[i] = (idx < NB) ? bs[idx] : 0;
        s += tv[i];
    }
    sums[t] = s;
    __syncthreads();
    for (int off = 1; off < 1024; off <<= 1) {
        int v = (t >= off) ? sums[t - off] : 0;
        __syncthreads();
        sums[t] += v;
        __syncthreads();
    }
    int ex = (t == 0) ? 0 : sums[t - 1];
#pragma unroll
    for (int i = 0; i < 4; ++i) {
        int idx = t * 4 + i;
        if (idx < NB) { bs[idx] = ex; ex += tv[i]; }
    }
    if (t == 0) bs[NB] = E;
}

// ---------------------------------------------------------------------------
// 3) Fill: bucket-sorted packed indices sidx[g][pos] = e | rowloc<<28.
//    Position = bstart + chunk offset + LDS rank. No global atomics.
// ---------------------------------------------------------------------------
__global__ __launch_bounds__(256) void fill_kernel(
    const int* __restrict__ edge_rows,
    const unsigned* __restrict__ pcnt,
    const int* __restrict__ bstart,
    unsigned* __restrict__ sidx)
{
    __shared__ int base[NB];
    __shared__ int cur[NB];
    const int blk = blockIdx.x, g = blockIdx.y, tid = threadIdx.x;
    const unsigned* pc = pcnt + ((size_t)g * NCHK + blk) * NB;
    const int* bs = bstart + (size_t)g * (NB + 1);
    for (int i = tid; i < NB; i += 256) {
        base[i] = bs[i] + (int)pc[i];
        cur[i] = 0;
    }
    __syncthreads();
    const int* rows = edge_rows + (size_t)g * E + (size_t)blk * CHUNK;
    unsigned* sg = sidx + (size_t)g * E;
    for (int i = tid; i < CHUNK; i += 256) {
        int r = rows[i];
        int b = r >> BSH;
        int rank = atomicAdd(&cur[b], 1);
        sg[base[b] + rank] = (unsigned)(blk * CHUNK + i) | ((unsigned)(r & 15) << 28);
    }
}

// ---------------------------------------------------------------------------
// 4) Fused: per bucket (16 rows). Per graph: LDS counting-sort by rowloc,
//    per-wave register gather (4 rows, bf16 x), acc->LDS, GEMM-accumulate
//    through 16KB LDS W chunks (bias-initialized regs). One out write.
// ---------------------------------------------------------------------------
__global__ __launch_bounds__(256) void fused_kernel(
    const unsigned* __restrict__ xb,      // [N][64] packed bf16 pairs
    const unsigned* __restrict__ sidx,    // [L][E]
    const int* __restrict__ bstart,       // [L][NB+1]
    const int* __restrict__ edge_cols,    // [L][E]
    const float* __restrict__ edge_vals,  // [L][E]
    const float* __restrict__ W,          // [L][D][D]
    const float* __restrict__ mix,        // [L]
    const float* __restrict__ bias,       // [D]
    float* __restrict__ out)              // [N][D]
{
    // union region: gather {su[CAP], ssorted[CAP], rc[16], rcur[16]} | gemm {wc[32][128]}
    __shared__ __align__(16) char smem[32 * D * sizeof(float)];  // 16 KB
    unsigned* su      = (unsigned*)smem;            // [CAP]  4 KB
    unsigned* ssorted = (unsigned*)(smem + 4096);   // [CAP]  4 KB
    int* rc           = (int*)(smem + 8192);        // [16]
    int* rcur         = rc + 16;                    // [16]
    float* wc         = (float*)smem;               // [32][128] 16 KB (GEMM phase)
    __shared__ float accL[16][D];                   // 8 KB

    const int b = blockIdx.x, tid = threadIdx.x;
    const int lane = tid & 63, wave = tid >> 6;
    const int f0 = 2 * lane;

    float2 oa[4];
    {
        float2 bv = *reinterpret_cast<const float2*>(bias + f0);
#pragma unroll
        for (int r = 0; r < 4; ++r) oa[r] = bv;
    }

    for (int l = 0; l < L; ++l) {
        const unsigned* sg = sidx + (size_t)l * E;
        const int* cols_g = edge_cols + (size_t)l * E;
        const float* vals_g = edge_vals + (size_t)l * E;
        const int beg = bstart[l * (NB + 1) + b];
        const int end = bstart[l * (NB + 1) + b + 1];
        const int cnt = end - beg;
        const int scnt = cnt < CAP ? cnt : CAP;

        if (tid < 16) rc[tid] = 0;
        for (int i = tid; i < scnt; i += 256) su[i] = sg[beg + i];
        __syncthreads();
        for (int i = tid; i < scnt; i += 256) atomicAdd(&rc[su[i] >> 28], 1);
        __syncthreads();
        if (tid == 0) {
            int run = 0;
#pragma unroll
            for (int r = 0; r < 16; ++r) {
                int c = rc[r];
                rc[r] = run;
                rcur[r] = run;
                run += c;
            }
        }
        __syncthreads();
        for (int i = tid; i < scnt; i += 256) {
            unsigned v = su[i];
            int p = atomicAdd(&rcur[v >> 28], 1);
            ssorted[p] = v;
        }
        __syncthreads();

        float2 g2[4];
#pragma unroll
        for (int r = 0; r < 4; ++r) {
            g2[r] = make_float2(0.f, 0.f);
            const int rl = 4 * wave + r;
            const int s0 = rc[rl];
            const int s1 = (rl < 15) ? rc[rl + 1] : scnt;
            for (int j = s0; j < s1; ++j) {
                unsigned v = ssorted[j];
                int e = v & 0x0FFFFFFF;
                float val = vals_g[e];
                int c = cols_g[e];
                unsigned xv = xb[(size_t)c * 64 + lane];
                g2[r].x = fmaf(val, __uint_as_float(xv << 16), g2[r].x);
                g2[r].y = fmaf(val, __uint_as_float(xv & 0xFFFF0000u), g2[r].y);
            }
        }
        // overflow tail (statistically never; correctness net)
        for (int j = beg + scnt; j < end; ++j) {
            unsigned v = sg[j];
            int rl = (int)(v >> 28);
            if ((rl >> 2) == wave) {
                int e = v & 0x0FFFFFFF;
                float val = vals_g[e];
                int c = cols_g[e];
                unsigned xv = xb[(size_t)c * 64 + lane];
#pragma unroll
                for (int r = 0; r < 4; ++r)
                    if ((rl & 3) == r) {
                        g2[r].x = fmaf(val, __uint_as_float(xv << 16), g2[r].x);
                        g2[r].y = fmaf(val, __uint_as_float(xv & 0xFFFF0000u), g2[r].y);
                    }
            }
        }
#pragma unroll
        for (int r = 0; r < 4; ++r)
            *reinterpret_cast<float2*>(&accL[4 * wave + r][f0]) = g2[r];
        __syncthreads();   // accL visible; su/ssorted dead -> wc may overwrite

        const float m = mix[l];
        const float4* wsrc = reinterpret_cast<const float4*>(W + (size_t)l * D * D);
        for (int kc = 0; kc < 4; ++kc) {
            for (int i = tid; i < 1024; i += 256) {
                float4 t = wsrc[kc * 1024 + i];
                reinterpret_cast<float4*>(wc)[i] =
                    make_float4(m * t.x, m * t.y, m * t.z, m * t.w);
            }
            __syncthreads();
#pragma unroll
            for (int d4 = 0; d4 < 8; ++d4) {
                float4 av[4];
#pragma unroll
                for (int r = 0; r < 4; ++r)
                    av[r] = *reinterpret_cast<const float4*>(
                        &accL[4 * wave + r][kc * 32 + d4 * 4]);
#pragma unroll
                for (int jj = 0; jj < 4; ++jj) {
                    float2 wv = reinterpret_cast<const float2*>(wc)[(d4 * 4 + jj) * 64 + lane];
#pragma unroll
                    for (int r = 0; r < 4; ++r) {
                        float s = (jj == 0) ? av[r].x
                                : (jj == 1) ? av[r].y
                                : (jj == 2) ? av[r].z
                                            : av[r].w;
                        oa[r].x = fmaf(s, wv.x, oa[r].x);
                        oa[r].y = fmaf(s, wv.y, oa[r].y);
                    }
                }
            }
            __syncthreads();
        }
    }

#pragma unroll
    for (int r = 0; r < 4; ++r) {
        int row = b * 16 + 4 * wave + r;
        *reinterpret_cast<float2*>(out + (size_t)row * D + f0) = oa[r];
    }
}

extern "C" void kernel_launch(void* const* d_in, const int* in_sizes, int n_in,
                              void* d_out, int out_size, void* d_ws, size_t ws_size,
                              hipStream_t stream)
{
    const float* x         = (const float*)d_in[0];
    const int*   edge_rows = (const int*)d_in[1];
    const int*   edge_cols = (const int*)d_in[2];
    const float* edge_vals = (const float*)d_in[3];
    const float* W         = (const float*)d_in[4];
    const float* mix       = (const float*)d_in[5];
    const float* bias      = (const float*)d_in[6];
    float* out = (float*)d_out;

    // Workspace (~30.7 MB): sidx [L][E] uint (12.8 MB) | pcnt [L][NCHK][NB]
    // (5 MB) | bstart [L][NB+1] (50 KB) | xb [N][64] uint (12.8 MB)
    unsigned* sidx   = (unsigned*)d_ws;
    unsigned* pcnt   = sidx + (size_t)L * E;
    int*      bstart = (int*)(pcnt + (size_t)L * NCHK * NB);
    unsigned* xb     = (unsigned*)(bstart + (size_t)L * (NB + 1));

    cvt_x_kernel<<<(N * D / 2) / 256, 256, 0, stream>>>(x, xb);
    bucket_hist_kernel<<<dim3(NCHK, L), 256, 0, stream>>>(edge_rows, pcnt);
    scan1_kernel<<<dim3((NB + 255) / 256, L), 256, 0, stream>>>(pcnt, bstart);
    scan2_kernel<<<L, 1024, 0, stream>>>(bstart);
    fill_kernel<<<dim3(NCHK, L), 256, 0, stream>>>(edge_rows, pcnt, bstart, sidx);
    fused_kernel<<<NB, 256, 0, stream>>>(xb, sidx, bstart, edge_cols, edge_vals,
                                         W, mix, bias, out);
}